// Round 3
// baseline (679.861 us; speedup 1.0000x reference)
//
#include <hip/hip_runtime.h>

#define B_ 128
#define D_ 512
#define K_ 512
#define SQ_ 128
#define ST_ 12
#define NEG_INF_ -1000000000.0f

__device__ __forceinline__ float wave_sum(float part) {
    #pragma unroll
    for (int off = 32; off > 0; off >>= 1) part += __shfl_xor(part, off);
    return part;
}
__device__ __forceinline__ float dot4(float4 a, const float* v) {
    return a.x * v[0] + a.y * v[1] + a.z * v[2] + a.w * v[3];
}

// One block per batch row b. Entire MAC cell fused; fp32 in/out; NO workspace.
__global__ __launch_bounds__(512) void mac_fused(
    const float* __restrict__ x,    const float* __restrict__ hc,
    const float* __restrict__ hm,   const float* __restrict__ knl,
    const float* __restrict__ question, const float* __restrict__ qrep,
    const float* __restrict__ W_qs, const float* __restrict__ b_qs,
    const float* __restrict__ Wcq,  const float* __restrict__ bcq,
    const float* __restrict__ Wf,   const float* __restrict__ bfv,
    const float* __restrict__ rWm,  const float* __restrict__ rbm,
    const float* __restrict__ rWk,  const float* __restrict__ rbk,
    const float* __restrict__ rWd,  const float* __restrict__ rbd,
    const float* __restrict__ rWr,  const float* __restrict__ rbr,
    const float* __restrict__ Wm1,  const float* __restrict__ bm1,
    const float* __restrict__ Wca,  const float* __restrict__ bca,
    const float* __restrict__ Wm2,  const float* __restrict__ bm2,
    const float* __restrict__ Ws,   const float* __restrict__ bs,
    const float* __restrict__ Wm3,  const float* __restrict__ bm3,
    float* __restrict__ out)
{
    const int b    = blockIdx.x;
    const int tid  = threadIdx.x;
    const int lane = tid & 63;
    const int wv   = tid >> 6;   // 0..7

    __shared__ float sTmp[D_];   // xq, later nc*Wca
    __shared__ float sQs[D_];
    __shared__ float sPc[D_];    // prev_control
    __shared__ float sP[D_];     // cq*Wf
    __shared__ float sF[SQ_];    // focus / q-attn
    __shared__ float sNc[D_];    // new_control
    __shared__ float sV[D_];     // v = nc*Wr
    __shared__ float sG[D_];     // g = rm * w_bot
    __shared__ float sU[D_];     // u (rank-1 collapse vector)
    __shared__ float sPm[D_];    // prev_memory
    __shared__ float sAtt[K_];   // retrieve logits -> r-attn
    __shared__ float sRead[D_];
    __shared__ float sM1[D_];
    __shared__ float sMsa[D_];
    __shared__ float sRed[D_];   // reduction scratch
    __shared__ float sCa[ST_];
    __shared__ float sCs[ST_];
    __shared__ float sGate;

    // ---- stage per-b vectors ----
    sTmp[tid] = x[(size_t)b*D_ + tid] * qrep[(size_t)b*D_ + tid];
    sPc[tid]  = hc[(size_t)(b*ST_)*D_ + tid];
    sPm[tid]  = hm[(size_t)(b*ST_)*D_ + tid];
    __syncthreads();

    // ---- quest_state = (x*qrep)@W_qs + b_qs  (column-coalesced matvec) ----
    {
        float acc = b_qs[tid];
        #pragma unroll 8
        for (int i = 0; i < D_; ++i) acc += sTmp[i] * W_qs[(size_t)i*D_ + tid];
        sQs[tid] = acc;
    }
    __syncthreads();

    // ---- cq = [qs, pc]@Wcq + bcq ; p = cq*Wf ----
    {
        float acc = bcq[tid];
        #pragma unroll 8
        for (int i = 0; i < D_; ++i) acc += sQs[i] * Wcq[(size_t)i*D_ + tid];
        #pragma unroll 8
        for (int i = 0; i < D_; ++i) acc += sPc[i] * Wcq[(size_t)(D_ + i)*D_ + tid];
        sP[tid] = acc * Wf[tid];
    }
    __syncthreads();

    // ---- focus[s] = question[b,s,:].p + bf  (8 waves x 16 rows, float4) ----
    {
        const float bfs = bfv[0];
        for (int t = 0; t < 16; ++t) {
            const int s = wv * 16 + t;
            const float4* qrow = reinterpret_cast<const float4*>(
                question + ((size_t)(b*SQ_) + s)*D_);
            float part = dot4(qrow[lane*2],     &sP[lane*8]) +
                         dot4(qrow[lane*2 + 1], &sP[lane*8 + 4]);
            part = wave_sum(part);
            if (lane == 0) sF[s] = part + bfs;
        }
    }
    __syncthreads();

    // ---- softmax over SQ=128 (fold 1/SQ for the mean) ----
    {
        sRed[tid] = (tid < SQ_) ? sF[tid] : -3.0e38f;
        __syncthreads();
        for (int off = 256; off > 0; off >>= 1) {
            if (tid < off) sRed[tid] = fmaxf(sRed[tid], sRed[tid + off]);
            __syncthreads();
        }
        const float mx = sRed[0];
        __syncthreads();
        float ex = 0.f;
        if (tid < SQ_) ex = expf(sF[tid] - mx);
        sRed[tid] = (tid < SQ_) ? ex : 0.f;
        __syncthreads();
        for (int off = 256; off > 0; off >>= 1) {
            if (tid < off) sRed[tid] += sRed[tid + off];
            __syncthreads();
        }
        const float inv = 1.f / (sRed[0] * (float)SQ_);
        __syncthreads();
        if (tid < SQ_) sF[tid] = ex * inv;
    }
    __syncthreads();

    // ---- new_control (coalesced over d=tid) ----
    {
        float ncv = 0.f;
        #pragma unroll 4
        for (int s = 0; s < SQ_; ++s)
            ncv += sF[s] * question[((size_t)(b*SQ_) + s)*D_ + tid];
        sNc[tid] = ncv;
        sV[tid]  = ncv * rWr[tid];
    }
    __syncthreads();

    // ---- rank-1 collapse: rm, Wd row-dots, g, u, c ----
    float cc;
    {
        float rmv = rbm[tid];
        #pragma unroll 8
        for (int i = 0; i < D_; ++i) rmv += sPm[i] * rWm[(size_t)i*D_ + tid];

        const float4* rowT = reinterpret_cast<const float4*>(rWd + (size_t)tid*D_);
        const float4* rowB = reinterpret_cast<const float4*>(rWd + (size_t)(D_ + tid)*D_);
        float u1 = 0.f, w2 = 0.f;
        #pragma unroll 8
        for (int i = 0; i < 128; ++i) {
            u1 += dot4(rowT[i], &sV[i*4]);
            w2 += dot4(rowB[i], &sV[i*4]);
        }
        sG[tid] = rmv * w2;
        __syncthreads();

        const float4* rowK = reinterpret_cast<const float4*>(rWk + (size_t)tid*D_);
        float u2 = 0.f;
        #pragma unroll 8
        for (int i = 0; i < 128; ++i) u2 += dot4(rowK[i], &sG[i*4]);
        sU[tid] = u1 + u2;

        sRed[tid] = rbd[tid] * sV[tid] + rbk[tid] * sG[tid];
        __syncthreads();
        for (int off = 256; off > 0; off >>= 1) {
            if (tid < off) sRed[tid] += sRed[tid + off];
            __syncthreads();
        }
        cc = sRed[0] + rbr[0];
    }
    __syncthreads();

    // ---- retrieve logits: 8 waves x 64 rows, float4 ----
    for (int r = 0; r < 64; ++r) {
        const int k = wv * 64 + r;
        const float4* krow = reinterpret_cast<const float4*>(
            knl + ((size_t)(b*K_) + k)*D_);
        float part = dot4(krow[lane*2],     &sU[lane*8]) +
                     dot4(krow[lane*2 + 1], &sU[lane*8 + 4]);
        part = wave_sum(part);
        if (lane == 0) sAtt[k] = part + cc;
    }
    __syncthreads();

    // ---- softmax over K=512 (fold 1/K for the mean) ----
    {
        sRed[tid] = sAtt[tid];
        __syncthreads();
        for (int off = 256; off > 0; off >>= 1) {
            if (tid < off) sRed[tid] = fmaxf(sRed[tid], sRed[tid + off]);
            __syncthreads();
        }
        const float mx = sRed[0];
        __syncthreads();
        const float ex = expf(sAtt[tid] - mx);
        sRed[tid] = ex;
        __syncthreads();
        for (int off = 256; off > 0; off >>= 1) {
            if (tid < off) sRed[tid] += sRed[tid + off];
            __syncthreads();
        }
        const float inv = 1.f / (sRed[0] * (float)K_);
        __syncthreads();
        sAtt[tid] = ex * inv;
    }
    __syncthreads();

    // ---- read[d] = sum_k att[k]*kn[b,k,d]  (coalesced; rows L2/L3-hot) ----
    {
        float rd = 0.f;
        #pragma unroll 4
        for (int k = 0; k < K_; ++k)
            rd += sAtt[k] * knl[((size_t)(b*K_) + k)*D_ + tid];
        sRead[tid] = rd;
    }
    __syncthreads();

    // ---- m1 = [pm, read]@Wm1 + bm1 ; stage nc*Wca ----
    {
        float m1 = bm1[tid];
        #pragma unroll 8
        for (int i = 0; i < D_; ++i) m1 += sPm[i] * Wm1[(size_t)i*D_ + tid];
        #pragma unroll 8
        for (int i = 0; i < D_; ++i) m1 += sRead[i] * Wm1[(size_t)(D_ + i)*D_ + tid];
        sM1[tid] = m1;
        sTmp[tid] = sNc[tid] * Wca[tid];
    }
    __syncthreads();

    // ---- ca[t] = hc[b,t,:].(nc*Wca) + bca ----
    {
        const float bcaf = bca[0];
        for (int rep = 0; rep < 2; ++rep) {
            const int r = (rep == 0) ? wv : ((wv < 4) ? 8 + wv : -1);
            if (r >= 0) {
                const float4* hrow = reinterpret_cast<const float4*>(
                    hc + ((size_t)(b*ST_) + r)*D_);
                float part = dot4(hrow[lane*2],     &sTmp[lane*8]) +
                             dot4(hrow[lane*2 + 1], &sTmp[lane*8 + 4]);
                part = wave_sum(part);
                if (lane == 0) sCa[r] = part + bcaf;
            }
        }
    }
    __syncthreads();

    // ---- masked softmax over 12 steps (serial, tiny) ----
    if (tid == 0) {
        float vals[ST_];
        float mx = -3.0e38f;
        for (int t = 0; t < ST_; ++t) {
            float v = sCa[t];
            if (v == 0.0f) v = v + NEG_INF_;
            vals[t] = v;
            mx = fmaxf(mx, v);
        }
        float sum = 0.f;
        for (int t = 0; t < ST_; ++t) { float e = expf(vals[t] - mx); sCs[t] = e; sum += e; }
        const float is = 1.f / sum;
        for (int t = 0; t < ST_; ++t) sCs[t] *= is;
    }
    __syncthreads();

    // ---- msa ----
    {
        float msa = 0.f;
        #pragma unroll
        for (int t = 0; t < ST_; ++t)
            msa += sCs[t] * hm[((size_t)(b*ST_) + t)*D_ + tid];
        sMsa[tid] = msa;
    }

    // ---- gate = sigmoid(nc.Wm3 + bm3) ----
    {
        sRed[tid] = sNc[tid] * Wm3[tid];
        __syncthreads();
        for (int off = 256; off > 0; off >>= 1) {
            if (tid < off) sRed[tid] += sRed[tid + off];
            __syncthreads();
        }
        if (tid == 0) sGate = 1.f / (1.f + expf(-(sRed[0] + bm3[0])));
    }
    __syncthreads();
    const float gate = sGate;

    // ---- mp = m1@Wm2 + bm2 + msa@Ws + bs ; new_memory ----
    float mp = bm2[tid] + bs[tid];
    #pragma unroll 8
    for (int i = 0; i < D_; ++i) mp += sM1[i] * Wm2[(size_t)i*D_ + tid];
    #pragma unroll 8
    for (int i = 0; i < D_; ++i) mp += sMsa[i] * Ws[(size_t)i*D_ + tid];
    const float nm = mp * gate + (1.f - gate) * sPm[tid];

    // ---- outputs: (2, B, ST, D) fp32 ----
    float* outC = out + (size_t)b*ST_*D_;
    float* outM = out + ((size_t)B_ + b)*ST_*D_;
    outC[tid] = sNc[tid];
    outM[tid] = nm;
    for (int t = 1; t < ST_; ++t) {
        outC[(size_t)t*D_ + tid] = hc[((size_t)(b*ST_) + (t - 1))*D_ + tid];
        outM[(size_t)t*D_ + tid] = hm[((size_t)(b*ST_) + (t - 1))*D_ + tid];
    }
}

extern "C" void kernel_launch(void* const* d_in, const int* in_sizes, int n_in,
                              void* d_out, int out_size, void* d_ws, size_t ws_size,
                              hipStream_t stream) {
    (void)in_sizes; (void)n_in; (void)d_ws; (void)ws_size; (void)out_size;
    mac_fused<<<B_, 512, 0, stream>>>(
        (const float*)d_in[0],  (const float*)d_in[1],
        (const float*)d_in[2],  (const float*)d_in[3],
        (const float*)d_in[4],  (const float*)d_in[5],
        (const float*)d_in[6],  (const float*)d_in[7],
        (const float*)d_in[8],  (const float*)d_in[9],
        (const float*)d_in[10], (const float*)d_in[11],
        (const float*)d_in[12], (const float*)d_in[13],
        (const float*)d_in[14], (const float*)d_in[15],
        (const float*)d_in[16], (const float*)d_in[17],
        (const float*)d_in[18], (const float*)d_in[19],
        (const float*)d_in[20], (const float*)d_in[21],
        (const float*)d_in[22], (const float*)d_in[23],
        (const float*)d_in[24], (const float*)d_in[25],
        (const float*)d_in[26], (const float*)d_in[27],
        (const float*)d_in[28], (const float*)d_in[29],
        (float*)d_out);
}

// Round 4
// 408.844 us; speedup vs baseline: 1.6629x; 1.6629x over previous
//
#include <hip/hip_runtime.h>

#define B_ 128
#define D_ 512
#define K_ 512
#define SQ_ 128
#define ST_ 12
#define NEG_INF_ -1000000000.0f

typedef unsigned int uint_t;

__device__ __forceinline__ float wave_sum(float part) {
    #pragma unroll
    for (int off = 32; off > 0; off >>= 1) part += __shfl_xor(part, off);
    return part;
}
__device__ __forceinline__ float wave_max(float part) {
    #pragma unroll
    for (int off = 32; off > 0; off >>= 1) part = fmaxf(part, __shfl_xor(part, off));
    return part;
}
__device__ __forceinline__ float dot4(float4 a, const float* v) {
    return a.x * v[0] + a.y * v[1] + a.z * v[2] + a.w * v[3];
}
__device__ __forceinline__ float dot4f(float4 a, float4 b) {
    return a.x * b.x + a.y * b.y + a.z * b.z + a.w * b.w;
}

// ws layout (floats)
#define WS_QS  0
#define WS_RM  65536
#define WS_P   131072
#define WS_FL  196608   /* B*SQ = 16384 */
#define WS_NC  212992
#define WS_V   278528
#define WS_U   344064
#define WS_G   409600
#define WS_KL  475136
#define WS_RD  540672
#define WS_M1  606208
#define WS_MSA 671744
#define WS_GP  737280   /* B */
#define WS_TOTAL_FLOATS 737408

// ============ k1: qs-tiles | rm-tiles | output copies | gp zero ============
__global__ __launch_bounds__(512) void kInit(
    const float* __restrict__ x, const float* __restrict__ qrep,
    const float* __restrict__ W_qs, const float* __restrict__ b_qs,
    const float* __restrict__ hm, const float* __restrict__ rWm,
    const float* __restrict__ rbm, const float* __restrict__ hc,
    float* __restrict__ ws, float* __restrict__ out)
{
    const int blk = blockIdx.x;
    const int tid = threadIdx.x;
    __shared__ float sIn[D_];
    __shared__ float sPart[512];

    if (blk < 1024) {
        // column-matvec tiles: blk<512 -> qs, else rm
        const bool is_qs = (blk < 512);
        const int q  = is_qs ? blk : (blk - 512);
        const int b  = q >> 2, dt = q & 3;
        sIn[tid] = is_qs ? (x[(size_t)b*D_ + tid] * qrep[(size_t)b*D_ + tid])
                         : hm[(size_t)(b*ST_)*D_ + tid];
        __syncthreads();
        const int isid = tid >> 7, dd = tid & 127, d = dt*128 + dd;
        const float* W  = is_qs ? W_qs : rWm;
        const float* Wp = W + (size_t)(isid*128)*D_ + d;
        const float* ip = sIn + isid*128;
        float acc = 0.f;
        #pragma unroll 16
        for (int j = 0; j < 128; ++j) acc += ip[j] * Wp[(size_t)j*D_];
        sPart[tid] = acc;
        __syncthreads();
        if (tid < 128) {
            const int d2 = dt*128 + tid;
            const float bias = is_qs ? b_qs[d2] : rbm[d2];
            float* dst = ws + (is_qs ? WS_QS : WS_RM);
            dst[(size_t)b*D_ + d2] = bias + sPart[tid] + sPart[tid+128]
                                   + sPart[tid+256] + sPart[tid+384];
        }
    } else if (blk < 1280) {
        // shifted-row copies: rows 1..11 of controls/memories
        const int c = blk - 1024;           // 0..255
        const int pair = c >> 7, b = c & 127;
        const float* src = (pair == 0) ? hc : hm;
        float* dst = out + ((size_t)(pair*B_ + b))*ST_*D_;
        const float* s = src + (size_t)(b*ST_)*D_;
        for (int r = 0; r < ST_ - 1; ++r)
            dst[(size_t)(r + 1)*D_ + tid] = s[(size_t)r*D_ + tid];
    } else {
        if (tid < B_) ws[WS_GP + tid] = 0.f;
    }
}

// ============ k2: cq = [qs, pc]@Wcq + bcq ; p = cq*Wf ============
__global__ __launch_bounds__(512) void kCq(
    const float* __restrict__ hc, const float* __restrict__ Wcq,
    const float* __restrict__ bcq, const float* __restrict__ Wf,
    float* __restrict__ ws)
{
    const int blk = blockIdx.x, tid = threadIdx.x;
    const int b = blk >> 2, dt = blk & 3;
    __shared__ float sIn[2*D_];
    __shared__ float sPart[512];
    sIn[tid]       = ws[WS_QS + (size_t)b*D_ + tid];
    sIn[D_ + tid]  = hc[(size_t)(b*ST_)*D_ + tid];
    __syncthreads();
    const int isid = tid >> 7, dd = tid & 127, d = dt*128 + dd;
    const float* Wp = Wcq + (size_t)(isid*256)*D_ + d;
    const float* ip = sIn + isid*256;
    float acc = 0.f;
    #pragma unroll 16
    for (int j = 0; j < 256; ++j) acc += ip[j] * Wp[(size_t)j*D_];
    sPart[tid] = acc;
    __syncthreads();
    if (tid < 128) {
        const int d2 = dt*128 + tid;
        const float cq = bcq[d2] + sPart[tid] + sPart[tid+128]
                       + sPart[tid+256] + sPart[tid+384];
        ws[WS_P + (size_t)b*D_ + d2] = cq * Wf[d2];
    }
}

// ============ k3: focus logits (bias dropped: softmax-invariant) ============
__global__ __launch_bounds__(256) void kFocus(
    const float* __restrict__ question, const float* __restrict__ ws_p,
    float* __restrict__ ws_fl)
{
    const int tid = threadIdx.x, lane = tid & 63;
    const int row = blockIdx.x * 4 + (tid >> 6);     // b*SQ + s
    const int b = row >> 7;
    const float4* qr = reinterpret_cast<const float4*>(question + (size_t)row*D_);
    const float4* pr = reinterpret_cast<const float4*>(ws_p + (size_t)b*D_);
    const float part = wave_sum(dot4f(qr[lane*2], pr[lane*2]) +
                                dot4f(qr[lane*2+1], pr[lane*2+1]));
    if (lane == 0) ws_fl[row] = part;
}

// ============ k4: focus softmax + new_control tile + v + gate partial ============
__global__ __launch_bounds__(512) void kNc(
    const float* __restrict__ question, const float* __restrict__ rWr,
    const float* __restrict__ Wm3, float* __restrict__ ws)
{
    const int blk = blockIdx.x, tid = threadIdx.x;
    const int b = blk >> 2, dt = blk & 3;
    __shared__ float sAtt[SQ_];
    __shared__ float sPart[512];
    __shared__ float sRed2[2];

    float l = 0.f;
    if (tid < SQ_) { l = ws[WS_FL + (size_t)b*SQ_ + tid]; sAtt[tid] = l; }
    __syncthreads();
    if (tid < 64) {
        float m = wave_max(fmaxf(sAtt[tid], sAtt[tid + 64]));
        if (tid == 0) sRed2[0] = m;
    }
    __syncthreads();
    float ex = 0.f;
    if (tid < SQ_) { ex = expf(l - sRed2[0]); sAtt[tid] = ex; }
    __syncthreads();
    if (tid < 64) {
        float s = wave_sum(sAtt[tid] + sAtt[tid + 64]);
        if (tid == 0) sRed2[1] = s;
    }
    __syncthreads();
    if (tid < SQ_) sAtt[tid] = ex / (sRed2[1] * (float)SQ_);
    __syncthreads();

    const int ssid = tid >> 7, dd = tid & 127, d = dt*128 + dd;
    float acc = 0.f;
    #pragma unroll 8
    for (int j = 0; j < 32; ++j) {
        const int s = ssid*32 + j;
        acc += sAtt[s] * question[((size_t)(b*SQ_ + s))*D_ + d];
    }
    sPart[tid] = acc;
    __syncthreads();
    if (tid < 128) {
        const int d2 = dt*128 + tid;
        const float nc = sPart[tid] + sPart[tid+128] + sPart[tid+256] + sPart[tid+384];
        ws[WS_NC + (size_t)b*D_ + d2] = nc;
        ws[WS_V  + (size_t)b*D_ + d2] = nc * rWr[d2];
        sPart[tid] = nc * Wm3[d2];
    }
    __syncthreads();
    if (tid < 64) {
        float s = wave_sum(sPart[tid] + sPart[tid + 64]);
        if (tid == 0) atomicAdd(&ws[WS_GP + b], s);
    }
}

// ============ k5: u1[b,t] = WdTop[t,:].v[b]; g = rm * (WdBot[t,:].v[b]) ============
__global__ __launch_bounds__(512) void kG1(
    const float* __restrict__ rWd, float* __restrict__ ws)
{
    const int blk = blockIdx.x, tid = threadIdx.x;
    const int bt = blk >> 4, tt = blk & 15;        // 8 b-tiles x 16 t-tiles
    const int b0 = bt*16, t0 = tt*32;
    __shared__ float sV[16*520];
    for (int r = 0; r < 16; ++r)
        sV[r*520 + tid] = ws[WS_V + (size_t)(b0 + r)*D_ + tid];
    __syncthreads();
    const int bl = tid & 15, tl = tid >> 4;
    const int b = b0 + bl, t = t0 + tl;
    const float4* rT = reinterpret_cast<const float4*>(rWd + (size_t)t*D_);
    const float4* rB = reinterpret_cast<const float4*>(rWd + (size_t)(D_ + t)*D_);
    const float* vv = sV + bl*520;
    float u1 = 0.f, w2 = 0.f;
    #pragma unroll 8
    for (int i = 0; i < 128; ++i) {
        u1 += dot4(rT[i], vv + i*4);
        w2 += dot4(rB[i], vv + i*4);
    }
    ws[WS_U + (size_t)b*D_ + t] = u1;
    ws[WS_G + (size_t)b*D_ + t] = ws[WS_RM + (size_t)b*D_ + t] * w2;
}

// ============ k6: u[b,t] += rWk[t,:].g[b] ============
__global__ __launch_bounds__(512) void kG2(
    const float* __restrict__ rWk, float* __restrict__ ws)
{
    const int blk = blockIdx.x, tid = threadIdx.x;
    const int bt = blk >> 4, tt = blk & 15;
    const int b0 = bt*16, t0 = tt*32;
    __shared__ float sG[16*520];
    for (int r = 0; r < 16; ++r)
        sG[r*520 + tid] = ws[WS_G + (size_t)(b0 + r)*D_ + tid];
    __syncthreads();
    const int bl = tid & 15, tl = tid >> 4;
    const int b = b0 + bl, t = t0 + tl;
    const float4* rK = reinterpret_cast<const float4*>(rWk + (size_t)t*D_);
    const float* gg = sG + bl*520;
    float u2 = 0.f;
    #pragma unroll 8
    for (int i = 0; i < 128; ++i) u2 += dot4(rK[i], gg + i*4);
    ws[WS_U + (size_t)b*D_ + t] += u2;
}

// ============ k7: knowledge logits (c dropped: softmax-invariant) ============
__global__ __launch_bounds__(256) void kKlog(
    const float* __restrict__ knl, const float* __restrict__ ws_u,
    float* __restrict__ ws_kl)
{
    const int tid = threadIdx.x, lane = tid & 63;
    const int row = blockIdx.x * 4 + (tid >> 6);     // b*K + k
    const int b = row >> 9;
    const float4* kr = reinterpret_cast<const float4*>(knl + (size_t)row*D_);
    const float4* ur = reinterpret_cast<const float4*>(ws_u + (size_t)b*D_);
    const float part = wave_sum(dot4f(kr[lane*2], ur[lane*2]) +
                                dot4f(kr[lane*2+1], ur[lane*2+1]));
    if (lane == 0) ws_kl[row] = part;
}

// ============ k8: retrieve softmax + read tile ============
__global__ __launch_bounds__(512) void kRead(
    const float* __restrict__ knl, float* __restrict__ ws)
{
    const int blk = blockIdx.x, tid = threadIdx.x;
    const int b = blk >> 2, dt = blk & 3;
    __shared__ float sAtt[K_];
    __shared__ float sPart[512];
    __shared__ float sRed2[2];

    const float l = ws[WS_KL + (size_t)b*K_ + tid];
    sAtt[tid] = l;
    __syncthreads();
    if (tid < 64) {
        float m = sAtt[tid];
        #pragma unroll
        for (int j = 1; j < 8; ++j) m = fmaxf(m, sAtt[tid + 64*j]);
        m = wave_max(m);
        if (tid == 0) sRed2[0] = m;
    }
    __syncthreads();
    const float ex = expf(l - sRed2[0]);
    sAtt[tid] = ex;
    __syncthreads();
    if (tid < 64) {
        float s = 0.f;
        #pragma unroll
        for (int j = 0; j < 8; ++j) s += sAtt[tid + 64*j];
        s = wave_sum(s);
        if (tid == 0) sRed2[1] = s;
    }
    __syncthreads();
    sAtt[tid] = ex / (sRed2[1] * (float)K_);
    __syncthreads();

    const int ksid = tid >> 7, dd = tid & 127, d = dt*128 + dd;
    float acc = 0.f;
    #pragma unroll 8
    for (int j = 0; j < 128; ++j) {
        const int k = ksid*128 + j;
        acc += sAtt[k] * knl[((size_t)(b*K_ + k))*D_ + d];
    }
    sPart[tid] = acc;
    __syncthreads();
    if (tid < 128)
        ws[WS_RD + (size_t)b*D_ + dt*128 + tid] =
            sPart[tid] + sPart[tid+128] + sPart[tid+256] + sPart[tid+384];
}

// ============ k9: ca + masked softmax + msa (per b) ============
__global__ __launch_bounds__(512) void kSmall(
    const float* __restrict__ hc, const float* __restrict__ hm,
    const float* __restrict__ Wca, const float* __restrict__ bca,
    float* __restrict__ ws)
{
    const int b = blockIdx.x, tid = threadIdx.x;
    const int lane = tid & 63, wv = tid >> 6;
    __shared__ float sW[D_];
    __shared__ float sCa[ST_];
    __shared__ float sCs[ST_];
    sW[tid] = ws[WS_NC + (size_t)b*D_ + tid] * Wca[tid];
    __syncthreads();
    const float bcaf = bca[0];
    for (int rep = 0; rep < 2; ++rep) {
        const int r = (rep == 0) ? wv : ((wv < 4) ? 8 + wv : -1);
        if (r >= 0) {
            const float4* hrow = reinterpret_cast<const float4*>(
                hc + ((size_t)(b*ST_) + r)*D_);
            float part = wave_sum(dot4(hrow[lane*2], &sW[lane*8]) +
                                  dot4(hrow[lane*2+1], &sW[lane*8+4]));
            if (lane == 0) sCa[r] = part + bcaf;
        }
    }
    __syncthreads();
    if (tid == 0) {
        float vals[ST_], mx = -3.0e38f;
        for (int t = 0; t < ST_; ++t) {
            float v = sCa[t];
            if (v == 0.0f) v = v + NEG_INF_;
            vals[t] = v; mx = fmaxf(mx, v);
        }
        float sum = 0.f;
        for (int t = 0; t < ST_; ++t) { float e = expf(vals[t] - mx); sCs[t] = e; sum += e; }
        const float is = 1.f / sum;
        for (int t = 0; t < ST_; ++t) sCs[t] *= is;
    }
    __syncthreads();
    float msa = 0.f;
    #pragma unroll
    for (int t = 0; t < ST_; ++t)
        msa += sCs[t] * hm[((size_t)(b*ST_) + t)*D_ + tid];
    ws[WS_MSA + (size_t)b*D_ + tid] = msa;
}

// ============ k10: m1 = [pm, read]@Wm1 + bm1 ============
__global__ __launch_bounds__(512) void kM1(
    const float* __restrict__ hm, const float* __restrict__ Wm1,
    const float* __restrict__ bm1, float* __restrict__ ws)
{
    const int blk = blockIdx.x, tid = threadIdx.x;
    const int b = blk >> 2, dt = blk & 3;
    __shared__ float sIn[2*D_];
    __shared__ float sPart[512];
    sIn[tid]      = hm[(size_t)(b*ST_)*D_ + tid];
    sIn[D_ + tid] = ws[WS_RD + (size_t)b*D_ + tid];
    __syncthreads();
    const int isid = tid >> 7, dd = tid & 127, d = dt*128 + dd;
    const float* Wp = Wm1 + (size_t)(isid*256)*D_ + d;
    const float* ip = sIn + isid*256;
    float acc = 0.f;
    #pragma unroll 16
    for (int j = 0; j < 256; ++j) acc += ip[j] * Wp[(size_t)j*D_];
    sPart[tid] = acc;
    __syncthreads();
    if (tid < 128) {
        const int d2 = dt*128 + tid;
        ws[WS_M1 + (size_t)b*D_ + d2] = bm1[d2] + sPart[tid] + sPart[tid+128]
                                      + sPart[tid+256] + sPart[tid+384];
    }
}

// ============ k11: mp, gate, new_memory, output row0 ============
__global__ __launch_bounds__(512) void kFinal(
    const float* __restrict__ hm, const float* __restrict__ Wm2,
    const float* __restrict__ bm2, const float* __restrict__ Ws,
    const float* __restrict__ bs, const float* __restrict__ bm3,
    const float* __restrict__ ws, float* __restrict__ out)
{
    const int blk = blockIdx.x, tid = threadIdx.x;
    const int b = blk >> 2, dt = blk & 3;
    __shared__ float sIn[2*D_];
    __shared__ float sPart[512];
    sIn[tid]      = ws[WS_M1  + (size_t)b*D_ + tid];
    sIn[D_ + tid] = ws[WS_MSA + (size_t)b*D_ + tid];
    __syncthreads();
    const int isid = tid >> 7, dd = tid & 127, d = dt*128 + dd;
    const float* Mat = (isid < 2) ? Wm2 : Ws;
    const int ibase = (isid & 1) * 256;
    const float* ip = sIn + (isid >> 1)*D_ + ibase;
    const float* Wp = Mat + (size_t)ibase*D_ + d;
    float acc = 0.f;
    #pragma unroll 16
    for (int j = 0; j < 256; ++j) acc += ip[j] * Wp[(size_t)j*D_];
    sPart[tid] = acc;
    __syncthreads();
    if (tid < 128) {
        const int d2 = dt*128 + tid;
        const float mp = bm2[d2] + bs[d2] + sPart[tid] + sPart[tid+128]
                       + sPart[tid+256] + sPart[tid+384];
        const float gate = 1.f / (1.f + expf(-(ws[WS_GP + b] + bm3[0])));
        const float pm = hm[(size_t)(b*ST_)*D_ + d2];
        const float nm = mp * gate + (1.f - gate) * pm;
        out[(size_t)(b*ST_)*D_ + d2] = ws[WS_NC + (size_t)b*D_ + d2];
        out[((size_t)(B_ + b))*ST_*D_ + d2] = nm;
    }
}

// ===================== fallback: round-3 fused kernel (proven) =====================
__global__ __launch_bounds__(512) void mac_fused(
    const float* __restrict__ x,    const float* __restrict__ hc,
    const float* __restrict__ hm,   const float* __restrict__ knl,
    const float* __restrict__ question, const float* __restrict__ qrep,
    const float* __restrict__ W_qs, const float* __restrict__ b_qs,
    const float* __restrict__ Wcq,  const float* __restrict__ bcq,
    const float* __restrict__ Wf,   const float* __restrict__ bfv,
    const float* __restrict__ rWm,  const float* __restrict__ rbm,
    const float* __restrict__ rWk,  const float* __restrict__ rbk,
    const float* __restrict__ rWd,  const float* __restrict__ rbd,
    const float* __restrict__ rWr,  const float* __restrict__ rbr,
    const float* __restrict__ Wm1,  const float* __restrict__ bm1,
    const float* __restrict__ Wca,  const float* __restrict__ bca,
    const float* __restrict__ Wm2,  const float* __restrict__ bm2,
    const float* __restrict__ Ws,   const float* __restrict__ bs,
    const float* __restrict__ Wm3,  const float* __restrict__ bm3,
    float* __restrict__ out)
{
    const int b    = blockIdx.x;
    const int tid  = threadIdx.x;
    const int lane = tid & 63;
    const int wv   = tid >> 6;

    __shared__ float sTmp[D_];
    __shared__ float sQs[D_];
    __shared__ float sPc[D_];
    __shared__ float sP[D_];
    __shared__ float sF[SQ_];
    __shared__ float sNc[D_];
    __shared__ float sV[D_];
    __shared__ float sG[D_];
    __shared__ float sU[D_];
    __shared__ float sPm[D_];
    __shared__ float sAtt[K_];
    __shared__ float sRead[D_];
    __shared__ float sM1[D_];
    __shared__ float sMsa[D_];
    __shared__ float sRed[D_];
    __shared__ float sCa[ST_];
    __shared__ float sCs[ST_];
    __shared__ float sGate;

    sTmp[tid] = x[(size_t)b*D_ + tid] * qrep[(size_t)b*D_ + tid];
    sPc[tid]  = hc[(size_t)(b*ST_)*D_ + tid];
    sPm[tid]  = hm[(size_t)(b*ST_)*D_ + tid];
    __syncthreads();
    {
        float acc = b_qs[tid];
        #pragma unroll 8
        for (int i = 0; i < D_; ++i) acc += sTmp[i] * W_qs[(size_t)i*D_ + tid];
        sQs[tid] = acc;
    }
    __syncthreads();
    {
        float acc = bcq[tid];
        #pragma unroll 8
        for (int i = 0; i < D_; ++i) acc += sQs[i] * Wcq[(size_t)i*D_ + tid];
        #pragma unroll 8
        for (int i = 0; i < D_; ++i) acc += sPc[i] * Wcq[(size_t)(D_ + i)*D_ + tid];
        sP[tid] = acc * Wf[tid];
    }
    __syncthreads();
    {
        const float bfs = bfv[0];
        for (int t = 0; t < 16; ++t) {
            const int s = wv * 16 + t;
            const float4* qrow = reinterpret_cast<const float4*>(
                question + ((size_t)(b*SQ_) + s)*D_);
            float part = dot4(qrow[lane*2], &sP[lane*8]) +
                         dot4(qrow[lane*2 + 1], &sP[lane*8 + 4]);
            part = wave_sum(part);
            if (lane == 0) sF[s] = part + bfs;
        }
    }
    __syncthreads();
    {
        sRed[tid] = (tid < SQ_) ? sF[tid] : -3.0e38f;
        __syncthreads();
        for (int off = 256; off > 0; off >>= 1) {
            if (tid < off) sRed[tid] = fmaxf(sRed[tid], sRed[tid + off]);
            __syncthreads();
        }
        const float mx = sRed[0];
        __syncthreads();
        float ex = 0.f;
        if (tid < SQ_) ex = expf(sF[tid] - mx);
        sRed[tid] = (tid < SQ_) ? ex : 0.f;
        __syncthreads();
        for (int off = 256; off > 0; off >>= 1) {
            if (tid < off) sRed[tid] += sRed[tid + off];
            __syncthreads();
        }
        const float inv = 1.f / (sRed[0] * (float)SQ_);
        __syncthreads();
        if (tid < SQ_) sF[tid] = ex * inv;
    }
    __syncthreads();
    {
        float ncv = 0.f;
        #pragma unroll 4
        for (int s = 0; s < SQ_; ++s)
            ncv += sF[s] * question[((size_t)(b*SQ_) + s)*D_ + tid];
        sNc[tid] = ncv;
        sV[tid]  = ncv * rWr[tid];
    }
    __syncthreads();
    float cc;
    {
        float rmv = rbm[tid];
        #pragma unroll 8
        for (int i = 0; i < D_; ++i) rmv += sPm[i] * rWm[(size_t)i*D_ + tid];
        const float4* rowT = reinterpret_cast<const float4*>(rWd + (size_t)tid*D_);
        const float4* rowB = reinterpret_cast<const float4*>(rWd + (size_t)(D_ + tid)*D_);
        float u1 = 0.f, w2 = 0.f;
        #pragma unroll 8
        for (int i = 0; i < 128; ++i) {
            u1 += dot4(rowT[i], &sV[i*4]);
            w2 += dot4(rowB[i], &sV[i*4]);
        }
        sG[tid] = rmv * w2;
        __syncthreads();
        const float4* rowK = reinterpret_cast<const float4*>(rWk + (size_t)tid*D_);
        float u2 = 0.f;
        #pragma unroll 8
        for (int i = 0; i < 128; ++i) u2 += dot4(rowK[i], &sG[i*4]);
        sU[tid] = u1 + u2;
        sRed[tid] = rbd[tid] * sV[tid] + rbk[tid] * sG[tid];
        __syncthreads();
        for (int off = 256; off > 0; off >>= 1) {
            if (tid < off) sRed[tid] += sRed[tid + off];
            __syncthreads();
        }
        cc = sRed[0] + rbr[0];
    }
    __syncthreads();
    for (int r = 0; r < 64; ++r) {
        const int k = wv * 64 + r;
        const float4* krow = reinterpret_cast<const float4*>(
            knl + ((size_t)(b*K_) + k)*D_);
        float part = dot4(krow[lane*2], &sU[lane*8]) +
                     dot4(krow[lane*2 + 1], &sU[lane*8 + 4]);
        part = wave_sum(part);
        if (lane == 0) sAtt[k] = part + cc;
    }
    __syncthreads();
    {
        sRed[tid] = sAtt[tid];
        __syncthreads();
        for (int off = 256; off > 0; off >>= 1) {
            if (tid < off) sRed[tid] = fmaxf(sRed[tid], sRed[tid + off]);
            __syncthreads();
        }
        const float mx = sRed[0];
        __syncthreads();
        const float ex = expf(sAtt[tid] - mx);
        sRed[tid] = ex;
        __syncthreads();
        for (int off = 256; off > 0; off >>= 1) {
            if (tid < off) sRed[tid] += sRed[tid + off];
            __syncthreads();
        }
        const float inv = 1.f / (sRed[0] * (float)K_);
        __syncthreads();
        sAtt[tid] = ex * inv;
    }
    __syncthreads();
    {
        float rd = 0.f;
        #pragma unroll 4
        for (int k = 0; k < K_; ++k)
            rd += sAtt[k] * knl[((size_t)(b*K_) + k)*D_ + tid];
        sRead[tid] = rd;
    }
    __syncthreads();
    {
        float m1 = bm1[tid];
        #pragma unroll 8
        for (int i = 0; i < D_; ++i) m1 += sPm[i] * Wm1[(size_t)i*D_ + tid];
        #pragma unroll 8
        for (int i = 0; i < D_; ++i) m1 += sRead[i] * Wm1[(size_t)(D_ + i)*D_ + tid];
        sM1[tid] = m1;
        sTmp[tid] = sNc[tid] * Wca[tid];
    }
    __syncthreads();
    {
        const float bcaf = bca[0];
        for (int rep = 0; rep < 2; ++rep) {
            const int r = (rep == 0) ? wv : ((wv < 4) ? 8 + wv : -1);
            if (r >= 0) {
                const float4* hrow = reinterpret_cast<const float4*>(
                    hc + ((size_t)(b*ST_) + r)*D_);
                float part = dot4(hrow[lane*2], &sTmp[lane*8]) +
                             dot4(hrow[lane*2 + 1], &sTmp[lane*8 + 4]);
                part = wave_sum(part);
                if (lane == 0) sCa[r] = part + bcaf;
            }
        }
    }
    __syncthreads();
    if (tid == 0) {
        float vals[ST_];
        float mx = -3.0e38f;
        for (int t = 0; t < ST_; ++t) {
            float v = sCa[t];
            if (v == 0.0f) v = v + NEG_INF_;
            vals[t] = v;
            mx = fmaxf(mx, v);
        }
        float sum = 0.f;
        for (int t = 0; t < ST_; ++t) { float e = expf(vals[t] - mx); sCs[t] = e; sum += e; }
        const float is = 1.f / sum;
        for (int t = 0; t < ST_; ++t) sCs[t] *= is;
    }
    __syncthreads();
    {
        float msa = 0.f;
        #pragma unroll
        for (int t = 0; t < ST_; ++t)
            msa += sCs[t] * hm[((size_t)(b*ST_) + t)*D_ + tid];
        sMsa[tid] = msa;
    }
    {
        sRed[tid] = sNc[tid] * Wm3[tid];
        __syncthreads();
        for (int off = 256; off > 0; off >>= 1) {
            if (tid < off) sRed[tid] += sRed[tid + off];
            __syncthreads();
        }
        if (tid == 0) sGate = 1.f / (1.f + expf(-(sRed[0] + bm3[0])));
    }
    __syncthreads();
    const float gate = sGate;
    float mp = bm2[tid] + bs[tid];
    #pragma unroll 8
    for (int i = 0; i < D_; ++i) mp += sM1[i] * Wm2[(size_t)i*D_ + tid];
    #pragma unroll 8
    for (int i = 0; i < D_; ++i) mp += sMsa[i] * Ws[(size_t)i*D_ + tid];
    const float nm = mp * gate + (1.f - gate) * sPm[tid];
    float* outC = out + (size_t)b*ST_*D_;
    float* outM = out + ((size_t)B_ + b)*ST_*D_;
    outC[tid] = sNc[tid];
    outM[tid] = nm;
    for (int t = 1; t < ST_; ++t) {
        outC[(size_t)t*D_ + tid] = hc[((size_t)(b*ST_) + (t - 1))*D_ + tid];
        outM[(size_t)t*D_ + tid] = hm[((size_t)(b*ST_) + (t - 1))*D_ + tid];
    }
}

extern "C" void kernel_launch(void* const* d_in, const int* in_sizes, int n_in,
                              void* d_out, int out_size, void* d_ws, size_t ws_size,
                              hipStream_t stream) {
    (void)in_sizes; (void)n_in; (void)out_size;
    const float* x    = (const float*)d_in[0];
    const float* hc   = (const float*)d_in[1];
    const float* hm   = (const float*)d_in[2];
    const float* knl  = (const float*)d_in[3];
    const float* qst  = (const float*)d_in[4];
    const float* qrep = (const float*)d_in[5];
    const float* W_qs = (const float*)d_in[6];
    const float* b_qs = (const float*)d_in[7];
    const float* Wcq  = (const float*)d_in[8];
    const float* bcq  = (const float*)d_in[9];
    const float* Wf   = (const float*)d_in[10];
    const float* bfv  = (const float*)d_in[11];
    const float* rWm  = (const float*)d_in[12];
    const float* rbm  = (const float*)d_in[13];
    const float* rWk  = (const float*)d_in[14];
    const float* rbk  = (const float*)d_in[15];
    const float* rWd  = (const float*)d_in[16];
    const float* rbd  = (const float*)d_in[17];
    const float* rWr  = (const float*)d_in[18];
    const float* rbr  = (const float*)d_in[19];
    const float* Wm1  = (const float*)d_in[20];
    const float* bm1  = (const float*)d_in[21];
    const float* Wca  = (const float*)d_in[22];
    const float* bca  = (const float*)d_in[23];
    const float* Wm2  = (const float*)d_in[24];
    const float* bm2  = (const float*)d_in[25];
    const float* Wsw  = (const float*)d_in[26];
    const float* bsw  = (const float*)d_in[27];
    const float* Wm3  = (const float*)d_in[28];
    const float* bm3  = (const float*)d_in[29];
    float* out = (float*)d_out;

    if (ws_size >= (size_t)WS_TOTAL_FLOATS * sizeof(float)) {
        float* ws = (float*)d_ws;
        kInit <<<1281, 512, 0, stream>>>(x, qrep, W_qs, b_qs, hm, rWm, rbm, hc, ws, out);
        kCq   <<<512,  512, 0, stream>>>(hc, Wcq, bcq, Wf, ws);
        kFocus<<<4096, 256, 0, stream>>>(qst, ws + WS_P, ws + WS_FL);
        kNc   <<<512,  512, 0, stream>>>(qst, rWr, Wm3, ws);
        kG1   <<<128,  512, 0, stream>>>(rWd, ws);
        kG2   <<<128,  512, 0, stream>>>(rWk, ws);
        kKlog <<<16384,256, 0, stream>>>(knl, ws + WS_U, ws + WS_KL);
        kRead <<<512,  512, 0, stream>>>(knl, ws);
        kSmall<<<128,  512, 0, stream>>>(hc, hm, Wca, bca, ws);
        kM1   <<<512,  512, 0, stream>>>(hm, Wm1, bm1, ws);
        kFinal<<<512,  512, 0, stream>>>(hm, Wm2, bm2, Wsw, bsw, bm3, ws, out);
    } else {
        mac_fused<<<B_, 512, 0, stream>>>(
            x, hc, hm, knl, qst, qrep, W_qs, b_qs, Wcq, bcq, Wf, bfv,
            rWm, rbm, rWk, rbk, rWd, rbd, rWr, rbr, Wm1, bm1, Wca, bca,
            Wm2, bm2, Wsw, bsw, Wm3, bm3, out);
    }
}

// Round 5
// 388.510 us; speedup vs baseline: 1.7499x; 1.0523x over previous
//
#include <hip/hip_runtime.h>

#define B_ 128
#define D_ 512
#define K_ 512
#define SQ_ 128
#define ST_ 12
#define NEG_INF_ -1000000000.0f

__device__ __forceinline__ float wave_sum(float part) {
    #pragma unroll
    for (int off = 32; off > 0; off >>= 1) part += __shfl_xor(part, off);
    return part;
}
__device__ __forceinline__ float dot4(float4 a, const float* v) {
    return a.x * v[0] + a.y * v[1] + a.z * v[2] + a.w * v[3];
}

// ws layout (floats)
#define WS_QS  0
#define WS_RM  65536
#define WS_P   131072
#define WS_NC  196608
#define WS_V   262144
#define WS_U   327680
#define WS_G   393216
#define WS_KP  458752   /* 512 partials x 516 (acc[512], m, l, pad) */
#define WS_GP  722944   /* B */
#define WS_M1  723072
#define WS_MSA 788608
#define WS_TOTAL_FLOATS 854144

// ============ k1: qs-tiles | rm-tiles | shifted output copies ============
__global__ __launch_bounds__(512) void kInit(
    const float* __restrict__ x, const float* __restrict__ qrep,
    const float* __restrict__ W_qs, const float* __restrict__ b_qs,
    const float* __restrict__ hm, const float* __restrict__ rWm,
    const float* __restrict__ rbm, const float* __restrict__ hc,
    float* __restrict__ ws, float* __restrict__ out)
{
    const int blk = blockIdx.x;
    const int tid = threadIdx.x;
    __shared__ float sIn[D_];
    __shared__ float sPart[512];

    if (blk < 1024) {
        const bool is_qs = (blk < 512);
        const int q  = is_qs ? blk : (blk - 512);
        const int b  = q >> 2, dt = q & 3;
        sIn[tid] = is_qs ? (x[(size_t)b*D_ + tid] * qrep[(size_t)b*D_ + tid])
                         : hm[(size_t)(b*ST_)*D_ + tid];
        __syncthreads();
        const int isid = tid >> 7, dd = tid & 127, d = dt*128 + dd;
        const float* W  = is_qs ? W_qs : rWm;
        const float* Wp = W + (size_t)(isid*128)*D_ + d;
        const float* ip = sIn + isid*128;
        float acc = 0.f;
        #pragma unroll 16
        for (int j = 0; j < 128; ++j) acc += ip[j] * Wp[(size_t)j*D_];
        sPart[tid] = acc;
        __syncthreads();
        if (tid < 128) {
            const int d2 = dt*128 + tid;
            const float bias = is_qs ? b_qs[d2] : rbm[d2];
            float* dst = ws + (is_qs ? WS_QS : WS_RM);
            dst[(size_t)b*D_ + d2] = bias + sPart[tid] + sPart[tid+128]
                                   + sPart[tid+256] + sPart[tid+384];
        }
    } else {
        const int c = blk - 1024;           // 0..255
        const int pair = c >> 7, b = c & 127;
        const float* src = (pair == 0) ? hc : hm;
        float* dst = out + ((size_t)(pair*B_ + b))*ST_*D_;
        const float* s = src + (size_t)(b*ST_)*D_;
        for (int r = 0; r < ST_ - 1; ++r)
            dst[(size_t)(r + 1)*D_ + tid] = s[(size_t)r*D_ + tid];
    }
}

// ============ k2: cq = [qs, pc]@Wcq + bcq ; p = cq*Wf ============
__global__ __launch_bounds__(512) void kCq(
    const float* __restrict__ hc, const float* __restrict__ Wcq,
    const float* __restrict__ bcq, const float* __restrict__ Wf,
    float* __restrict__ ws)
{
    const int blk = blockIdx.x, tid = threadIdx.x;
    const int b = blk >> 2, dt = blk & 3;
    __shared__ float sIn[2*D_];
    __shared__ float sPart[512];
    sIn[tid]       = ws[WS_QS + (size_t)b*D_ + tid];
    sIn[D_ + tid]  = hc[(size_t)(b*ST_)*D_ + tid];
    __syncthreads();
    const int isid = tid >> 7, dd = tid & 127, d = dt*128 + dd;
    const float* Wp = Wcq + (size_t)(isid*256)*D_ + d;
    const float* ip = sIn + isid*256;
    float acc = 0.f;
    #pragma unroll 16
    for (int j = 0; j < 256; ++j) acc += ip[j] * Wp[(size_t)j*D_];
    sPart[tid] = acc;
    __syncthreads();
    if (tid < 128) {
        const int d2 = dt*128 + tid;
        const float cq = bcq[d2] + sPart[tid] + sPart[tid+128]
                       + sPart[tid+256] + sPart[tid+384];
        ws[WS_P + (size_t)b*D_ + d2] = cq * Wf[d2];
    }
}

// ============ k3: question online-softmax -> nc, v, gate-dot (single pass) ============
__global__ __launch_bounds__(512) void kQnc(
    const float* __restrict__ question, const float* __restrict__ rWr,
    const float* __restrict__ Wm3, float* __restrict__ ws)
{
    const int b = blockIdx.x, tid = threadIdx.x;
    const int lane = tid & 63, wv = tid >> 6;
    __shared__ float sP[D_];
    __shared__ float sAcc[8][D_];
    __shared__ float sM[8], sL[8];
    __shared__ float sRed[512];
    sP[tid] = ws[WS_P + (size_t)b*D_ + tid];
    __syncthreads();
    // hoist this lane's p-fragment
    float p0=sP[lane*8],p1=sP[lane*8+1],p2=sP[lane*8+2],p3=sP[lane*8+3];
    float p4=sP[lane*8+4],p5=sP[lane*8+5],p6=sP[lane*8+6],p7=sP[lane*8+7];

    float m = -3.0e38f, l = 0.f;
    float a0=0,a1=0,a2=0,a3=0,a4=0,a5=0,a6=0,a7=0;
    for (int t = 0; t < 16; ++t) {
        const int s = wv*16 + t;
        const float4* qr = reinterpret_cast<const float4*>(
            question + ((size_t)(b*SQ_ + s))*D_);
        const float4 r0 = qr[lane*2], r1 = qr[lane*2+1];
        float part = r0.x*p0 + r0.y*p1 + r0.z*p2 + r0.w*p3
                   + r1.x*p4 + r1.y*p5 + r1.z*p6 + r1.w*p7;
        part = wave_sum(part);
        const float mn = fmaxf(m, part);
        const float sc = expf(m - mn);
        const float e  = expf(part - mn);
        l = l*sc + e;
        a0=a0*sc+e*r0.x; a1=a1*sc+e*r0.y; a2=a2*sc+e*r0.z; a3=a3*sc+e*r0.w;
        a4=a4*sc+e*r1.x; a5=a5*sc+e*r1.y; a6=a6*sc+e*r1.z; a7=a7*sc+e*r1.w;
        m = mn;
    }
    if (lane == 0) { sM[wv] = m; sL[wv] = l; }
    __syncthreads();
    float M = sM[0];
    #pragma unroll
    for (int w = 1; w < 8; ++w) M = fmaxf(M, sM[w]);
    const float msc = expf(m - M);
    sAcc[wv][lane*8  ] = a0*msc; sAcc[wv][lane*8+1] = a1*msc;
    sAcc[wv][lane*8+2] = a2*msc; sAcc[wv][lane*8+3] = a3*msc;
    sAcc[wv][lane*8+4] = a4*msc; sAcc[wv][lane*8+5] = a5*msc;
    sAcc[wv][lane*8+6] = a6*msc; sAcc[wv][lane*8+7] = a7*msc;
    __syncthreads();
    float L = 0.f;
    #pragma unroll
    for (int w = 0; w < 8; ++w) L += sL[w] * expf(sM[w] - M);
    float ncs = 0.f;
    #pragma unroll
    for (int w = 0; w < 8; ++w) ncs += sAcc[w][tid];
    const float nc = ncs / (L * (float)SQ_);
    ws[WS_NC + (size_t)b*D_ + tid] = nc;
    ws[WS_V  + (size_t)b*D_ + tid] = nc * rWr[tid];
    sRed[tid] = nc * Wm3[tid];
    __syncthreads();
    if (tid < 64) {
        float s = 0.f;
        #pragma unroll
        for (int j = 0; j < 8; ++j) s += sRed[tid + 64*j];
        s = wave_sum(s);
        if (tid == 0) ws[WS_GP + b] = s;
    }
}

// ============ k4: u1 = WdTop.v ; g = rm * (WdBot.v) ============
__global__ __launch_bounds__(512) void kG1(
    const float* __restrict__ rWd, float* __restrict__ ws)
{
    const int blk = blockIdx.x, tid = threadIdx.x;
    const int bt = blk >> 4, tt = blk & 15;
    const int b0 = bt*16, t0 = tt*32;
    __shared__ float sV[16*520];
    for (int r = 0; r < 16; ++r)
        sV[r*520 + tid] = ws[WS_V + (size_t)(b0 + r)*D_ + tid];
    __syncthreads();
    const int bl = tid & 15, tl = tid >> 4;
    const int b = b0 + bl, t = t0 + tl;
    const float4* rT = reinterpret_cast<const float4*>(rWd + (size_t)t*D_);
    const float4* rB = reinterpret_cast<const float4*>(rWd + (size_t)(D_ + t)*D_);
    const float* vv = sV + bl*520;
    float u1 = 0.f, w2 = 0.f;
    #pragma unroll 8
    for (int i = 0; i < 128; ++i) {
        u1 += dot4(rT[i], vv + i*4);
        w2 += dot4(rB[i], vv + i*4);
    }
    ws[WS_U + (size_t)b*D_ + t] = u1;
    ws[WS_G + (size_t)b*D_ + t] = ws[WS_RM + (size_t)b*D_ + t] * w2;
}

// ============ k5: u += rWk.g ============
__global__ __launch_bounds__(512) void kG2(
    const float* __restrict__ rWk, float* __restrict__ ws)
{
    const int blk = blockIdx.x, tid = threadIdx.x;
    const int bt = blk >> 4, tt = blk & 15;
    const int b0 = bt*16, t0 = tt*32;
    __shared__ float sG[16*520];
    for (int r = 0; r < 16; ++r)
        sG[r*520 + tid] = ws[WS_G + (size_t)(b0 + r)*D_ + tid];
    __syncthreads();
    const int bl = tid & 15, tl = tid >> 4;
    const int b = b0 + bl, t = t0 + tl;
    const float4* rK = reinterpret_cast<const float4*>(rWk + (size_t)t*D_);
    const float* gg = sG + bl*520;
    float u2 = 0.f;
    #pragma unroll 8
    for (int i = 0; i < 128; ++i) u2 += dot4(rK[i], gg + i*4);
    ws[WS_U + (size_t)b*D_ + t] += u2;
}

// ============ k6: knowledge SINGLE PASS online-softmax -> partial (m,l,acc) ============
// 4 blocks per b, 128 k-rows each; wave handles 16 rows with reg-resident acc.
__global__ __launch_bounds__(512) void kKRead(
    const float* __restrict__ knl, const float* __restrict__ ws_u,
    float* __restrict__ ws_kp)
{
    const int blk = blockIdx.x, tid = threadIdx.x;
    const int b = blk >> 2, kt = blk & 3;
    const int lane = tid & 63, wv = tid >> 6;
    __shared__ float sU[D_];
    __shared__ float sAcc[8][D_];
    __shared__ float sM[8], sL[8];
    sU[tid] = ws_u[(size_t)b*D_ + tid];
    __syncthreads();
    float u0=sU[lane*8],u1=sU[lane*8+1],u2=sU[lane*8+2],u3=sU[lane*8+3];
    float u4=sU[lane*8+4],u5=sU[lane*8+5],u6=sU[lane*8+6],u7=sU[lane*8+7];

    float m = -3.0e38f, l = 0.f;
    float a0=0,a1=0,a2=0,a3=0,a4=0,a5=0,a6=0,a7=0;
    for (int t = 0; t < 16; ++t) {
        const int k = kt*128 + wv*16 + t;
        const float4* kr = reinterpret_cast<const float4*>(
            knl + ((size_t)(b*K_ + k))*D_);
        const float4 r0 = kr[lane*2], r1 = kr[lane*2+1];
        float part = r0.x*u0 + r0.y*u1 + r0.z*u2 + r0.w*u3
                   + r1.x*u4 + r1.y*u5 + r1.z*u6 + r1.w*u7;
        part = wave_sum(part);
        const float mn = fmaxf(m, part);
        const float sc = expf(m - mn);
        const float e  = expf(part - mn);
        l = l*sc + e;
        a0=a0*sc+e*r0.x; a1=a1*sc+e*r0.y; a2=a2*sc+e*r0.z; a3=a3*sc+e*r0.w;
        a4=a4*sc+e*r1.x; a5=a5*sc+e*r1.y; a6=a6*sc+e*r1.z; a7=a7*sc+e*r1.w;
        m = mn;
    }
    if (lane == 0) { sM[wv] = m; sL[wv] = l; }
    __syncthreads();
    float M = sM[0];
    #pragma unroll
    for (int w = 1; w < 8; ++w) M = fmaxf(M, sM[w]);
    const float msc = expf(m - M);
    sAcc[wv][lane*8  ] = a0*msc; sAcc[wv][lane*8+1] = a1*msc;
    sAcc[wv][lane*8+2] = a2*msc; sAcc[wv][lane*8+3] = a3*msc;
    sAcc[wv][lane*8+4] = a4*msc; sAcc[wv][lane*8+5] = a5*msc;
    sAcc[wv][lane*8+6] = a6*msc; sAcc[wv][lane*8+7] = a7*msc;
    __syncthreads();
    float L = 0.f;
    #pragma unroll
    for (int w = 0; w < 8; ++w) L += sL[w] * expf(sM[w] - M);
    float a = 0.f;
    #pragma unroll
    for (int w = 0; w < 8; ++w) a += sAcc[w][tid];
    float* kp = ws_kp + (size_t)blk*516;
    kp[tid] = a;
    if (tid == 0) { kp[512] = M; kp[513] = L; }
}

// ============ k7: ca + masked softmax + msa (per b) ============
__global__ __launch_bounds__(512) void kSmall(
    const float* __restrict__ hc, const float* __restrict__ hm,
    const float* __restrict__ Wca, const float* __restrict__ bca,
    float* __restrict__ ws)
{
    const int b = blockIdx.x, tid = threadIdx.x;
    const int lane = tid & 63, wv = tid >> 6;
    __shared__ float sW[D_];
    __shared__ float sCa[ST_];
    __shared__ float sCs[ST_];
    sW[tid] = ws[WS_NC + (size_t)b*D_ + tid] * Wca[tid];
    __syncthreads();
    const float bcaf = bca[0];
    for (int rep = 0; rep < 2; ++rep) {
        const int r = (rep == 0) ? wv : ((wv < 4) ? 8 + wv : -1);
        if (r >= 0) {
            const float4* hrow = reinterpret_cast<const float4*>(
                hc + ((size_t)(b*ST_) + r)*D_);
            float part = wave_sum(dot4(hrow[lane*2], &sW[lane*8]) +
                                  dot4(hrow[lane*2+1], &sW[lane*8+4]));
            if (lane == 0) sCa[r] = part + bcaf;
        }
    }
    __syncthreads();
    if (tid == 0) {
        float vals[ST_], mx = -3.0e38f;
        for (int t = 0; t < ST_; ++t) {
            float v = sCa[t];
            if (v == 0.0f) v = v + NEG_INF_;
            vals[t] = v; mx = fmaxf(mx, v);
        }
        float sum = 0.f;
        for (int t = 0; t < ST_; ++t) { float e = expf(vals[t] - mx); sCs[t] = e; sum += e; }
        const float is = 1.f / sum;
        for (int t = 0; t < ST_; ++t) sCs[t] *= is;
    }
    __syncthreads();
    float msa = 0.f;
    #pragma unroll
    for (int t = 0; t < ST_; ++t)
        msa += sCs[t] * hm[((size_t)(b*ST_) + t)*D_ + tid];
    ws[WS_MSA + (size_t)b*D_ + tid] = msa;
}

// ============ k8: merge read partials + m1 = [pm, read]@Wm1 + bm1 ============
__global__ __launch_bounds__(512) void kM1(
    const float* __restrict__ hm, const float* __restrict__ Wm1,
    const float* __restrict__ bm1, float* __restrict__ ws)
{
    const int blk = blockIdx.x, tid = threadIdx.x;
    const int b = blk >> 2, dt = blk & 3;
    __shared__ float sIn[2*D_];
    __shared__ float sPart[512];
    // merge 4 knowledge partials -> read[b, tid]
    const float* kp = ws + WS_KP + (size_t)(b*4)*516;
    const float m0 = kp[512],        l0 = kp[513];
    const float m1v = kp[516+512],   l1 = kp[516+513];
    const float m2 = kp[2*516+512],  l2 = kp[2*516+513];
    const float m3 = kp[3*516+512],  l3 = kp[3*516+513];
    const float M = fmaxf(fmaxf(m0, m1v), fmaxf(m2, m3));
    const float e0 = expf(m0-M), e1 = expf(m1v-M), e2 = expf(m2-M), e3 = expf(m3-M);
    const float L = l0*e0 + l1*e1 + l2*e2 + l3*e3;
    const float rd = (kp[tid]*e0 + kp[516+tid]*e1 + kp[2*516+tid]*e2 + kp[3*516+tid]*e3)
                   / (L * (float)K_);
    sIn[tid]      = hm[(size_t)(b*ST_)*D_ + tid];
    sIn[D_ + tid] = rd;
    __syncthreads();
    const int isid = tid >> 7, dd = tid & 127, d = dt*128 + dd;
    const float* Wp = Wm1 + (size_t)(isid*256)*D_ + d;
    const float* ip = sIn + isid*256;
    float acc = 0.f;
    #pragma unroll 16
    for (int j = 0; j < 256; ++j) acc += ip[j] * Wp[(size_t)j*D_];
    sPart[tid] = acc;
    __syncthreads();
    if (tid < 128) {
        const int d2 = dt*128 + tid;
        ws[WS_M1 + (size_t)b*D_ + d2] = bm1[d2] + sPart[tid] + sPart[tid+128]
                                      + sPart[tid+256] + sPart[tid+384];
    }
}

// ============ k9: mp, gate, new_memory, output row0 ============
__global__ __launch_bounds__(512) void kFinal(
    const float* __restrict__ hm, const float* __restrict__ Wm2,
    const float* __restrict__ bm2, const float* __restrict__ Ws,
    const float* __restrict__ bs, const float* __restrict__ bm3,
    const float* __restrict__ ws, float* __restrict__ out)
{
    const int blk = blockIdx.x, tid = threadIdx.x;
    const int b = blk >> 2, dt = blk & 3;
    __shared__ float sIn[2*D_];
    __shared__ float sPart[512];
    sIn[tid]      = ws[WS_M1  + (size_t)b*D_ + tid];
    sIn[D_ + tid] = ws[WS_MSA + (size_t)b*D_ + tid];
    __syncthreads();
    const int isid = tid >> 7, dd = tid & 127, d = dt*128 + dd;
    const float* Mat = (isid < 2) ? Wm2 : Ws;
    const int ibase = (isid & 1) * 256;
    const float* ip = sIn + (isid >> 1)*D_ + ibase;
    const float* Wp = Mat + (size_t)ibase*D_ + d;
    float acc = 0.f;
    #pragma unroll 16
    for (int j = 0; j < 256; ++j) acc += ip[j] * Wp[(size_t)j*D_];
    sPart[tid] = acc;
    __syncthreads();
    if (tid < 128) {
        const int d2 = dt*128 + tid;
        const float mp = bm2[d2] + bs[d2] + sPart[tid] + sPart[tid+128]
                       + sPart[tid+256] + sPart[tid+384];
        const float gate = 1.f / (1.f + expf(-(ws[WS_GP + b] + bm3[0])));
        const float pm = hm[(size_t)(b*ST_)*D_ + d2];
        const float nm = mp * gate + (1.f - gate) * pm;
        out[(size_t)(b*ST_)*D_ + d2] = ws[WS_NC + (size_t)b*D_ + d2];
        out[((size_t)(B_ + b))*ST_*D_ + d2] = nm;
    }
}

// ===================== fallback: round-3 fused kernel (proven) =====================
__global__ __launch_bounds__(512) void mac_fused(
    const float* __restrict__ x,    const float* __restrict__ hc,
    const float* __restrict__ hm,   const float* __restrict__ knl,
    const float* __restrict__ question, const float* __restrict__ qrep,
    const float* __restrict__ W_qs, const float* __restrict__ b_qs,
    const float* __restrict__ Wcq,  const float* __restrict__ bcq,
    const float* __restrict__ Wf,   const float* __restrict__ bfv,
    const float* __restrict__ rWm,  const float* __restrict__ rbm,
    const float* __restrict__ rWk,  const float* __restrict__ rbk,
    const float* __restrict__ rWd,  const float* __restrict__ rbd,
    const float* __restrict__ rWr,  const float* __restrict__ rbr,
    const float* __restrict__ Wm1,  const float* __restrict__ bm1,
    const float* __restrict__ Wca,  const float* __restrict__ bca,
    const float* __restrict__ Wm2,  const float* __restrict__ bm2,
    const float* __restrict__ Ws,   const float* __restrict__ bs,
    const float* __restrict__ Wm3,  const float* __restrict__ bm3,
    float* __restrict__ out)
{
    const int b    = blockIdx.x;
    const int tid  = threadIdx.x;
    const int lane = tid & 63;
    const int wv   = tid >> 6;

    __shared__ float sTmp[D_];
    __shared__ float sQs[D_];
    __shared__ float sPc[D_];
    __shared__ float sP[D_];
    __shared__ float sF[SQ_];
    __shared__ float sNc[D_];
    __shared__ float sV[D_];
    __shared__ float sG[D_];
    __shared__ float sU[D_];
    __shared__ float sPm[D_];
    __shared__ float sAtt[K_];
    __shared__ float sRead[D_];
    __shared__ float sM1[D_];
    __shared__ float sMsa[D_];
    __shared__ float sRed[D_];
    __shared__ float sCa[ST_];
    __shared__ float sCs[ST_];
    __shared__ float sGate;

    sTmp[tid] = x[(size_t)b*D_ + tid] * qrep[(size_t)b*D_ + tid];
    sPc[tid]  = hc[(size_t)(b*ST_)*D_ + tid];
    sPm[tid]  = hm[(size_t)(b*ST_)*D_ + tid];
    __syncthreads();
    {
        float acc = b_qs[tid];
        #pragma unroll 8
        for (int i = 0; i < D_; ++i) acc += sTmp[i] * W_qs[(size_t)i*D_ + tid];
        sQs[tid] = acc;
    }
    __syncthreads();
    {
        float acc = bcq[tid];
        #pragma unroll 8
        for (int i = 0; i < D_; ++i) acc += sQs[i] * Wcq[(size_t)i*D_ + tid];
        #pragma unroll 8
        for (int i = 0; i < D_; ++i) acc += sPc[i] * Wcq[(size_t)(D_ + i)*D_ + tid];
        sP[tid] = acc * Wf[tid];
    }
    __syncthreads();
    {
        const float bfs = bfv[0];
        for (int t = 0; t < 16; ++t) {
            const int s = wv * 16 + t;
            const float4* qrow = reinterpret_cast<const float4*>(
                question + ((size_t)(b*SQ_) + s)*D_);
            float part = dot4(qrow[lane*2], &sP[lane*8]) +
                         dot4(qrow[lane*2 + 1], &sP[lane*8 + 4]);
            part = wave_sum(part);
            if (lane == 0) sF[s] = part + bfs;
        }
    }
    __syncthreads();
    {
        sRed[tid] = (tid < SQ_) ? sF[tid] : -3.0e38f;
        __syncthreads();
        for (int off = 256; off > 0; off >>= 1) {
            if (tid < off) sRed[tid] = fmaxf(sRed[tid], sRed[tid + off]);
            __syncthreads();
        }
        const float mx = sRed[0];
        __syncthreads();
        float ex = 0.f;
        if (tid < SQ_) ex = expf(sF[tid] - mx);
        sRed[tid] = (tid < SQ_) ? ex : 0.f;
        __syncthreads();
        for (int off = 256; off > 0; off >>= 1) {
            if (tid < off) sRed[tid] += sRed[tid + off];
            __syncthreads();
        }
        const float inv = 1.f / (sRed[0] * (float)SQ_);
        __syncthreads();
        if (tid < SQ_) sF[tid] = ex * inv;
    }
    __syncthreads();
    {
        float ncv = 0.f;
        #pragma unroll 4
        for (int s = 0; s < SQ_; ++s)
            ncv += sF[s] * question[((size_t)(b*SQ_) + s)*D_ + tid];
        sNc[tid] = ncv;
        sV[tid]  = ncv * rWr[tid];
    }
    __syncthreads();
    float cc;
    {
        float rmv = rbm[tid];
        #pragma unroll 8
        for (int i = 0; i < D_; ++i) rmv += sPm[i] * rWm[(size_t)i*D_ + tid];
        const float4* rowT = reinterpret_cast<const float4*>(rWd + (size_t)tid*D_);
        const float4* rowB = reinterpret_cast<const float4*>(rWd + (size_t)(D_ + tid)*D_);
        float u1 = 0.f, w2 = 0.f;
        #pragma unroll 8
        for (int i = 0; i < 128; ++i) {
            u1 += dot4(rowT[i], &sV[i*4]);
            w2 += dot4(rowB[i], &sV[i*4]);
        }
        sG[tid] = rmv * w2;
        __syncthreads();
        const float4* rowK = reinterpret_cast<const float4*>(rWk + (size_t)tid*D_);
        float u2 = 0.f;
        #pragma unroll 8
        for (int i = 0; i < 128; ++i) u2 += dot4(rowK[i], &sG[i*4]);
        sU[tid] = u1 + u2;
        sRed[tid] = rbd[tid] * sV[tid] + rbk[tid] * sG[tid];
        __syncthreads();
        for (int off = 256; off > 0; off >>= 1) {
            if (tid < off) sRed[tid] += sRed[tid + off];
            __syncthreads();
        }
        cc = sRed[0] + rbr[0];
    }
    __syncthreads();
    for (int r = 0; r < 64; ++r) {
        const int k = wv * 64 + r;
        const float4* krow = reinterpret_cast<const float4*>(
            knl + ((size_t)(b*K_) + k)*D_);
        float part = dot4(krow[lane*2], &sU[lane*8]) +
                     dot4(krow[lane*2 + 1], &sU[lane*8 + 4]);
        part = wave_sum(part);
        if (lane == 0) sAtt[k] = part + cc;
    }
    __syncthreads();
    {
        sRed[tid] = sAtt[tid];
        __syncthreads();
        for (int off = 256; off > 0; off >>= 1) {
            if (tid < off) sRed[tid] = fmaxf(sRed[tid], sRed[tid + off]);
            __syncthreads();
        }
        const float mx = sRed[0];
        __syncthreads();
        const float ex = expf(sAtt[tid] - mx);
        sRed[tid] = ex;
        __syncthreads();
        for (int off = 256; off > 0; off >>= 1) {
            if (tid < off) sRed[tid] += sRed[tid + off];
            __syncthreads();
        }
        const float inv = 1.f / (sRed[0] * (float)K_);
        __syncthreads();
        sAtt[tid] = ex * inv;
    }
    __syncthreads();
    {
        float rd = 0.f;
        #pragma unroll 4
        for (int k = 0; k < K_; ++k)
            rd += sAtt[k] * knl[((size_t)(b*K_) + k)*D_ + tid];
        sRead[tid] = rd;
    }
    __syncthreads();
    {
        float m1 = bm1[tid];
        #pragma unroll 8
        for (int i = 0; i < D_; ++i) m1 += sPm[i] * Wm1[(size_t)i*D_ + tid];
        #pragma unroll 8
        for (int i = 0; i < D_; ++i) m1 += sRead[i] * Wm1[(size_t)(D_ + i)*D_ + tid];
        sM1[tid] = m1;
        sTmp[tid] = sNc[tid] * Wca[tid];
    }
    __syncthreads();
    {
        const float bcaf = bca[0];
        for (int rep = 0; rep < 2; ++rep) {
            const int r = (rep == 0) ? wv : ((wv < 4) ? 8 + wv : -1);
            if (r >= 0) {
                const float4* hrow = reinterpret_cast<const float4*>(
                    hc + ((size_t)(b*ST_) + r)*D_);
                float part = dot4(hrow[lane*2], &sTmp[lane*8]) +
                             dot4(hrow[lane*2 + 1], &sTmp[lane*8 + 4]);
                part = wave_sum(part);
                if (lane == 0) sCa[r] = part + bcaf;
            }
        }
    }
    __syncthreads();
    if (tid == 0) {
        float vals[ST_];
        float mx = -3.0e38f;
        for (int t = 0; t < ST_; ++t) {
            float v = sCa[t];
            if (v == 0.0f) v = v + NEG_INF_;
            vals[t] = v;
            mx = fmaxf(mx, v);
        }
        float sum = 0.f;
        for (int t = 0; t < ST_; ++t) { float e = expf(vals[t] - mx); sCs[t] = e; sum += e; }
        const float is = 1.f / sum;
        for (int t = 0; t < ST_; ++t) sCs[t] *= is;
    }
    __syncthreads();
    {
        float msa = 0.f;
        #pragma unroll
        for (int t = 0; t < ST_; ++t)
            msa += sCs[t] * hm[((size_t)(b*ST_) + t)*D_ + tid];
        sMsa[tid] = msa;
    }
    {
        sRed[tid] = sNc[tid] * Wm3[tid];
        __syncthreads();
        for (int off = 256; off > 0; off >>= 1) {
            if (tid < off) sRed[tid] += sRed[tid + off];
            __syncthreads();
        }
        if (tid == 0) sGate = 1.f / (1.f + expf(-(sRed[0] + bm3[0])));
    }
    __syncthreads();
    const float gate = sGate;
    float mp = bm2[tid] + bs[tid];
    #pragma unroll 8
    for (int i = 0; i < D_; ++i) mp += sM1[i] * Wm2[(size_t)i*D_ + tid];
    #pragma unroll 8
    for (int i = 0; i < D_; ++i) mp += sMsa[i] * Ws[(size_t)i*D_ + tid];
    const float nm = mp * gate + (1.f - gate) * sPm[tid];
    float* outC = out + (size_t)b*ST_*D_;
    float* outM = out + ((size_t)B_ + b)*ST_*D_;
    outC[tid] = sNc[tid];
    outM[tid] = nm;
    for (int t = 1; t < ST_; ++t) {
        outC[(size_t)t*D_ + tid] = hc[((size_t)(b*ST_) + (t - 1))*D_ + tid];
        outM[(size_t)t*D_ + tid] = hm[((size_t)(b*ST_) + (t - 1))*D_ + tid];
    }
}

extern "C" void kernel_launch(void* const* d_in, const int* in_sizes, int n_in,
                              void* d_out, int out_size, void* d_ws, size_t ws_size,
                              hipStream_t stream) {
    (void)in_sizes; (void)n_in; (void)out_size;
    const float* x    = (const float*)d_in[0];
    const float* hc   = (const float*)d_in[1];
    const float* hm   = (const float*)d_in[2];
    const float* knl  = (const float*)d_in[3];
    const float* qst  = (const float*)d_in[4];
    const float* qrep = (const float*)d_in[5];
    const float* W_qs = (const float*)d_in[6];
    const float* b_qs = (const float*)d_in[7];
    const float* Wcq  = (const float*)d_in[8];
    const float* bcq  = (const float*)d_in[9];
    const float* Wf   = (const float*)d_in[10];
    const float* bfv  = (const float*)d_in[11];
    const float* rWm  = (const float*)d_in[12];
    const float* rbm  = (const float*)d_in[13];
    const float* rWk  = (const float*)d_in[14];
    const float* rbk  = (const float*)d_in[15];
    const float* rWd  = (const float*)d_in[16];
    const float* rbd  = (const float*)d_in[17];
    const float* rWr  = (const float*)d_in[18];
    const float* rbr  = (const float*)d_in[19];
    const float* Wm1  = (const float*)d_in[20];
    const float* bm1  = (const float*)d_in[21];
    const float* Wca  = (const float*)d_in[22];
    const float* bca  = (const float*)d_in[23];
    const float* Wm2  = (const float*)d_in[24];
    const float* bm2  = (const float*)d_in[25];
    const float* Wsw  = (const float*)d_in[26];
    const float* bsw  = (const float*)d_in[27];
    const float* Wm3  = (const float*)d_in[28];
    const float* bm3  = (const float*)d_in[29];
    float* out = (float*)d_out;

    if (ws_size >= (size_t)WS_TOTAL_FLOATS * sizeof(float)) {
        float* ws = (float*)d_ws;
        kInit  <<<1280, 512, 0, stream>>>(x, qrep, W_qs, b_qs, hm, rWm, rbm, hc, ws, out);
        kCq    <<<512,  512, 0, stream>>>(hc, Wcq, bcq, Wf, ws);
        kQnc   <<<128,  512, 0, stream>>>(qst, rWr, Wm3, ws);
        kG1    <<<128,  512, 0, stream>>>(rWd, ws);
        kG2    <<<128,  512, 0, stream>>>(rWk, ws);
        kKRead <<<512,  512, 0, stream>>>(knl, ws + WS_U, ws + WS_KP);
        kSmall <<<128,  512, 0, stream>>>(hc, hm, Wca, bca, ws);
        kM1    <<<512,  512, 0, stream>>>(hm, Wm1, bm1, ws);
        kFinal <<<512,  512, 0, stream>>>(hm, Wm2, bm2, Wsw, bsw, bm3, ws, out);
    } else {
        mac_fused<<<B_, 512, 0, stream>>>(
            x, hc, hm, knl, qst, qrep, W_qs, b_qs, Wcq, bcq, Wf, bfv,
            rWm, rbm, rWk, rbk, rWd, rbd, rWr, rbr, Wm1, bm1, Wca, bca,
            Wm2, bm2, Wsw, bsw, Wm3, bm3, out);
    }
}